// Round 5
// baseline (2102.980 us; speedup 1.0000x reference)
//
#include <hip/hip_runtime.h>

// RelGCN f32 pipeline, round 5.
//   prep  : h[r] = in @ W[r] + b[r]                  (verified, unchanged)
//   conv3 : accum[n][j] += sum_m adj[r][n][m] h[r][m][j]  via atomics over (r, k-slice)
//           A streamed global->reg (single-use), H LDS-staged, 8x8 thread tile
//           => FLOP/LDS-byte = 4 (>= 2 chip ratio) -> FMA-bound, not LDS-bound.
//   finish: dst = tanh(accum)
//   mfma_probe: 1-block diagnostic of the round-1 MFMA fragment layout;
//           encodes MISMATCH as +500us busy-sleep (dur_us side channel).

#define NN 8192

typedef __attribute__((ext_vector_type(4))) float float4v;
typedef __attribute__((ext_vector_type(8))) short short8v;

__device__ inline unsigned short f2bf(float f) {
  unsigned int u = __builtin_bit_cast(unsigned int, f);
  return (unsigned short)((u + 0x7FFFu + ((u >> 16) & 1u)) >> 16);  // RNE
}
__device__ inline float bfval(unsigned short s) {
  unsigned int u = ((unsigned int)s) << 16;
  return __builtin_bit_cast(float, u);
}

__global__ __launch_bounds__(256) void relgcn_prep(
    const float* __restrict__ in, const float* __restrict__ W,
    const float* __restrict__ b, float* __restrict__ h) {
  __shared__ float Ws[64 * 64];
  __shared__ float xs[8 * 64];
  const int tid = threadIdx.x;
  const int r = blockIdx.x >> 10;
  const int kb = blockIdx.x & 1023;
#pragma unroll
  for (int i = 0; i < 16; ++i) Ws[tid + i * 256] = W[r * 4096 + tid + i * 256];
  xs[tid] = in[(size_t)kb * 512 + tid];
  xs[tid + 256] = in[(size_t)kb * 512 + 256 + tid];
  __syncthreads();
#pragma unroll
  for (int idx = tid; idx < 512; idx += 256) {
    const int ml = idx >> 6;
    const int j = idx & 63;
    float acc = b[r * 64 + j];
#pragma unroll
    for (int f = 0; f < 64; ++f) acc += xs[ml * 64 + f] * Ws[f * 64 + j];
    h[((size_t)r << 19) + (size_t)(kb * 8 + ml) * 64 + j] = acc;
  }
}

// grid = 768: r = bid>>8, rowblock = (bid&255)>>3 (256 rows), kslice = bid&7 (1024 k)
__global__ __launch_bounds__(256, 2) void conv3(
    const float* __restrict__ adj, const float* __restrict__ h,
    float* __restrict__ accum) {
  __shared__ float hs[2][64 * 64];  // 32 KB, double-buffered 64k x 64j tile
  const int tid = threadIdx.x;
  const int r = blockIdx.x >> 8;
  const int rem = blockIdx.x & 255;
  const int rb = rem >> 3;
  const int ks = rem & 7;
  const int n0 = rb << 8;
  const int k0 = ks << 10;
  const int rg = tid >> 3;  // 0..31 -> 8 rows each
  const int cg = tid & 7;   // 0..7  -> 8 cols each
  const float* pa = adj + ((size_t)r << 26) + (size_t)(n0 + rg * 8) * NN + k0;
  const float* ph = h + ((size_t)r << 19) + (size_t)k0 * 64 + tid * 16;

  float acc[8][8] = {};

  {  // stage tile 0 -> buf 0
    float4v s0 = *(const float4v*)(ph);
    float4v s1 = *(const float4v*)(ph + 4);
    float4v s2 = *(const float4v*)(ph + 8);
    float4v s3 = *(const float4v*)(ph + 12);
    *(float4v*)&hs[0][tid * 16] = s0;
    *(float4v*)&hs[0][tid * 16 + 4] = s1;
    *(float4v*)&hs[0][tid * 16 + 8] = s2;
    *(float4v*)&hs[0][tid * 16 + 12] = s3;
  }
  __syncthreads();

  for (int t = 0; t < 16; ++t) {
    const int cur = t & 1;
    float4v p0, p1, p2, p3;
    if (t < 15) {  // issue next-tile loads early; latency hides under FMAs
      const float* pn = ph + (t + 1) * 4096;
      p0 = *(const float4v*)(pn);
      p1 = *(const float4v*)(pn + 4);
      p2 = *(const float4v*)(pn + 8);
      p3 = *(const float4v*)(pn + 12);
    }
    const float* H = &hs[cur][0];
    const float* pat = pa + t * 64;
#pragma unroll 2
    for (int k4 = 0; k4 < 16; ++k4) {
      float4v a[8];
#pragma unroll
      for (int i = 0; i < 8; ++i)
        a[i] = *(const float4v*)(pat + (size_t)i * NN + k4 * 4);
#pragma unroll
      for (int dk = 0; dk < 4; ++dk) {
        const float* hp = H + (k4 * 4 + dk) * 64 + cg * 8;
        const float4v h0 = *(const float4v*)(hp);
        const float4v h1 = *(const float4v*)(hp + 4);
#pragma unroll
        for (int i = 0; i < 8; ++i) {
          const float av = a[i][dk];
#pragma unroll
          for (int j = 0; j < 4; ++j) {
            acc[i][j] += av * h0[j];
            acc[i][j + 4] += av * h1[j];
          }
        }
      }
    }
    if (t < 15) {
      float* w = &hs[cur ^ 1][tid * 16];
      *(float4v*)(w) = p0;
      *(float4v*)(w + 4) = p1;
      *(float4v*)(w + 8) = p2;
      *(float4v*)(w + 12) = p3;
    }
    __syncthreads();
  }

  float* po = accum + (size_t)(n0 + rg * 8) * 64 + cg * 8;
#pragma unroll
  for (int i = 0; i < 8; ++i)
#pragma unroll
    for (int j = 0; j < 8; ++j)
      atomicAdd(po + (size_t)i * 64 + j, acc[i][j]);
}

__global__ __launch_bounds__(256) void finish_tanh(
    const float* __restrict__ accum, float* __restrict__ dst) {
  const int i = blockIdx.x * 256 + threadIdx.x;
  dst[i] = tanhf(accum[i]);
}

__global__ __launch_bounds__(256) void fill_sentinel(float* __restrict__ dst) {
  dst[blockIdx.x * 256 + threadIdx.x] = 7.0f;
}

// Diagnostic: verify round-1 MFMA fragment layout on real data (r=0, rows 0..15,
// K=128). Writes nothing; busy-sleeps ~500us iff MFMA result != scalar reference
// computed on the IDENTICAL bf16-rounded operands (tol 1e-5; bug signal ~1e-4).
__global__ __launch_bounds__(64) void mfma_probe(
    const float* __restrict__ adj, const float* __restrict__ h) {
  __shared__ unsigned short hb[128 * 64];  // swizzled bf16 h tile
  __shared__ float cm[16 * 64];
  __shared__ int flag;
  const int l = threadIdx.x;
  if (l == 0) flag = 0;
  for (int idx = l; idx < 128 * 64; idx += 64) {
    const int m = idx >> 6, j = idx & 63;
    hb[((m >> 3) * 64 + j) * 8 + (m & 7)] = f2bf(h[m * 64 + j]);
  }
  __syncthreads();
  const int lrow = l & 15, lk = l >> 4;
  float4v acc[4];
#pragma unroll
  for (int g = 0; g < 4; ++g) acc[g] = (float4v){0.f, 0.f, 0.f, 0.f};
#pragma unroll
  for (int c = 0; c < 4; ++c) {
    const int mm = c * 32;
    short8v av;
#pragma unroll
    for (int e = 0; e < 8; ++e)
      av[e] = (short)f2bf(adj[(size_t)lrow * NN + mm + lk * 8 + e]);
#pragma unroll
    for (int g = 0; g < 4; ++g) {
      const short8v bf = *(const short8v*)&hb[(mm / 8 + lk) * 512 + g * 128 + lrow * 8];
      acc[g] = __builtin_amdgcn_mfma_f32_16x16x32_bf16(av, bf, acc[g], 0, 0, 0);
    }
  }
#pragma unroll
  for (int g = 0; g < 4; ++g)
#pragma unroll
    for (int q = 0; q < 4; ++q)
      cm[(lk * 4 + q) * 64 + g * 16 + lrow] = acc[g][q];  // C: col=l&15, row=(l>>4)*4+q
  __syncthreads();
  const int row = l & 15, c0 = (l >> 4) * 16;
  float maxd = 0.f;
  for (int cc = 0; cc < 16; ++cc) {
    const int col = c0 + cc;
    float ref = 0.f;
    for (int m = 0; m < 128; ++m)
      ref += bfval(f2bf(adj[(size_t)row * NN + m])) * bfval(f2bf(h[m * 64 + col]));
    maxd = fmaxf(maxd, fabsf(cm[row * 64 + col] - ref));
  }
  if (maxd > 1e-5f) atomicOr(&flag, 1);
  __syncthreads();
  if (flag) {
    for (int i = 0; i < 150; ++i) __builtin_amdgcn_s_sleep(127);  // ~508us signal
  }
}

extern "C" void kernel_launch(void* const* d_in, const int* in_sizes, int n_in,
                              void* d_out, int out_size, void* d_ws, size_t ws_size,
                              hipStream_t stream) {
  const float* x   = (const float*)d_in[0];
  const float* adj = (const float*)d_in[1];
  const float* W1  = (const float*)d_in[2];
  const float* b1  = (const float*)d_in[3];
  const float* W2  = (const float*)d_in[4];
  const float* b2  = (const float*)d_in[5];
  float* out = (float*)d_out;

  const size_t ACC_B = (size_t)8192 * 64 * 4;      // 2 MB
  const size_t H_B   = (size_t)3 * 8192 * 64 * 4;  // 6 MB
  const size_t NEEDED = ACC_B + H_B + ACC_B;       // 10 MB
  if (ws_size < NEEDED) {
    fill_sentinel<<<2048, 256, 0, stream>>>(out);
    return;
  }
  float* accum = (float*)d_ws;
  float* h     = (float*)((char*)d_ws + ACC_B);
  float* t     = (float*)((char*)d_ws + ACC_B + H_B);

  // layer 1
  relgcn_prep<<<3 * 1024, 256, 0, stream>>>(x, W1, b1, h);
  mfma_probe<<<1, 64, 0, stream>>>(adj, h);  // diagnostic only
  hipMemsetAsync(accum, 0, ACC_B, stream);
  conv3<<<768, 256, 0, stream>>>(adj, h, accum);
  finish_tanh<<<2048, 256, 0, stream>>>(accum, t);
  // layer 2
  relgcn_prep<<<3 * 1024, 256, 0, stream>>>(t, W2, b2, h);
  hipMemsetAsync(accum, 0, ACC_B, stream);
  conv3<<<768, 256, 0, stream>>>(adj, h, accum);
  finish_tanh<<<2048, 256, 0, stream>>>(accum, out);
}

// Round 6
// 651.512 us; speedup vs baseline: 3.2278x; 3.2278x over previous
//
#include <hip/hip_runtime.h>

// RelGCN round 6: MFMA gemm (probe-verified fragment scheme), HBM-bound design.
//   prep2 : h[r]=in@W[r]+b[r] -> h (f32 natural, for probe) + hbf (bf16 swizzled)
//   gemm  : out = tanh( sum_{r,k} adj[r] (f32->bf16 in-reg) @ hbf[r] )  [f32 out]
//           512 blocks x 8 waves; block = 16 rows; waves split 768 (r,k)-chunks;
//           adj read once, coalesced 128B/row/chunk; B from L2-resident hbf (3MB);
//           LDS cross-wave reduce + fused tanh. No atomics, no extra passes.
//   mfma_probe: 1-block canary (verified round 5): +508us dur iff fragment bug.

#define NN 8192

typedef __attribute__((ext_vector_type(4))) float float4v;
typedef __attribute__((ext_vector_type(8))) short short8v;

__device__ inline unsigned short f2bf(float f) {
  unsigned int u = __builtin_bit_cast(unsigned int, f);
  return (unsigned short)((u + 0x7FFFu + ((u >> 16) & 1u)) >> 16);  // RNE
}
__device__ inline float bfval(unsigned short s) {
  unsigned int u = ((unsigned int)s) << 16;
  return __builtin_bit_cast(float, u);
}

// grid = 3*1024; writes h[r][m][j] (f32) and hbf[((r*1024+m/8)*64+j)*8+(m&7)] (bf16)
__global__ __launch_bounds__(256) void prep2(
    const float* __restrict__ in, const float* __restrict__ W,
    const float* __restrict__ b, float* __restrict__ h,
    unsigned short* __restrict__ hbf) {
  __shared__ float Ws[64 * 64];
  __shared__ float xs[8 * 64];
  const int tid = threadIdx.x;
  const int r = blockIdx.x >> 10;
  const int kb = blockIdx.x & 1023;
#pragma unroll
  for (int i = 0; i < 16; ++i) Ws[tid + i * 256] = W[r * 4096 + tid + i * 256];
  xs[tid] = in[(size_t)kb * 512 + tid];
  xs[tid + 256] = in[(size_t)kb * 512 + 256 + tid];
  __syncthreads();
#pragma unroll
  for (int idx = tid; idx < 512; idx += 256) {
    const int ml = idx >> 6;
    const int j = idx & 63;
    float acc = b[r * 64 + j];
#pragma unroll
    for (int f = 0; f < 64; ++f) acc += xs[ml * 64 + f] * Ws[f * 64 + j];
    h[((size_t)r << 19) + (size_t)(kb * 8 + ml) * 64 + j] = acc;
    hbf[((size_t)((r * 1024 + kb) * 64 + j)) * 8 + ml] = f2bf(acc);
  }
}

// grid = 512 blocks x 512 threads (8 waves). Block mb -> rows mb*16..+15.
__global__ __launch_bounds__(512) void gemm_mfma(
    const float* __restrict__ adj, const unsigned short* __restrict__ hbf,
    float* __restrict__ out) {
  __shared__ float red[8][16 * 64];
  const int tid = threadIdx.x;
  const int w = tid >> 6;
  const int l = tid & 63;
  const int lrow = l & 15;
  const int lk = l >> 4;
  const int mb = blockIdx.x;
  const float* parow = adj + (size_t)(mb * 16 + lrow) * NN + lk * 8;

  float4v acc[4];
#pragma unroll
  for (int g = 0; g < 4; ++g) acc[g] = (float4v){0.f, 0.f, 0.f, 0.f};

#pragma unroll 2
  for (int it = 0; it < 96; ++it) {
    const int c = it * 8 + w;            // chunk 0..767, each exactly once
    const int r = c >> 8;                // relation
    const int mm = (c & 255) << 5;       // k-offset within relation
    const float* pav = parow + ((size_t)r << 26) + mm;
    const float4v a0 = *(const float4v*)pav;
    const float4v a1 = *(const float4v*)(pav + 4);
    short8v av;
    av[0] = (short)f2bf(a0[0]); av[1] = (short)f2bf(a0[1]);
    av[2] = (short)f2bf(a0[2]); av[3] = (short)f2bf(a0[3]);
    av[4] = (short)f2bf(a1[0]); av[5] = (short)f2bf(a1[1]);
    av[6] = (short)f2bf(a1[2]); av[7] = (short)f2bf(a1[3]);
    const unsigned short* pb =
        hbf + (size_t)(r * 1024 + (mm >> 3) + lk) * 512 + lrow * 8;
#pragma unroll
    for (int g = 0; g < 4; ++g) {
      const short8v bf = *(const short8v*)(pb + g * 128);
      acc[g] = __builtin_amdgcn_mfma_f32_16x16x32_bf16(av, bf, acc[g], 0, 0, 0);
    }
  }

  // C layout (probe-verified): col = g*16 + (l&15), row = (l>>4)*4 + q
#pragma unroll
  for (int g = 0; g < 4; ++g)
#pragma unroll
    for (int q = 0; q < 4; ++q)
      red[w][(lk * 4 + q) * 64 + g * 16 + lrow] = acc[g][q];
  __syncthreads();
#pragma unroll
  for (int idx = tid; idx < 1024; idx += 512) {
    const int row = idx >> 6, col = idx & 63;
    float s = 0.f;
#pragma unroll
    for (int wb = 0; wb < 8; ++wb) s += red[wb][row * 64 + col];
    out[(size_t)(mb * 16 + row) * 64 + col] = tanhf(s);
  }
}

__global__ __launch_bounds__(256) void fill_sentinel(float* __restrict__ dst) {
  dst[blockIdx.x * 256 + threadIdx.x] = 7.0f;
}

// Canary (passed round 5): +508us busy-sleep iff MFMA != scalar ref on identical
// bf16-rounded operands (r=0, rows 0..15, K=128). Writes nothing.
__global__ __launch_bounds__(64) void mfma_probe(
    const float* __restrict__ adj, const float* __restrict__ h) {
  __shared__ unsigned short hb[128 * 64];
  __shared__ float cm[16 * 64];
  __shared__ int flag;
  const int l = threadIdx.x;
  if (l == 0) flag = 0;
  for (int idx = l; idx < 128 * 64; idx += 64) {
    const int m = idx >> 6, j = idx & 63;
    hb[((m >> 3) * 64 + j) * 8 + (m & 7)] = f2bf(h[m * 64 + j]);
  }
  __syncthreads();
  const int lrow = l & 15, lk = l >> 4;
  float4v acc[4];
#pragma unroll
  for (int g = 0; g < 4; ++g) acc[g] = (float4v){0.f, 0.f, 0.f, 0.f};
#pragma unroll
  for (int c = 0; c < 4; ++c) {
    const int mm = c * 32;
    short8v av;
#pragma unroll
    for (int e = 0; e < 8; ++e)
      av[e] = (short)f2bf(adj[(size_t)lrow * NN + mm + lk * 8 + e]);
#pragma unroll
    for (int g = 0; g < 4; ++g) {
      const short8v bf = *(const short8v*)&hb[(mm / 8 + lk) * 512 + g * 128 + lrow * 8];
      acc[g] = __builtin_amdgcn_mfma_f32_16x16x32_bf16(av, bf, acc[g], 0, 0, 0);
    }
  }
#pragma unroll
  for (int g = 0; g < 4; ++g)
#pragma unroll
    for (int q = 0; q < 4; ++q)
      cm[(lk * 4 + q) * 64 + g * 16 + lrow] = acc[g][q];
  __syncthreads();
  const int row = l & 15, c0 = (l >> 4) * 16;
  float maxd = 0.f;
  for (int cc = 0; cc < 16; ++cc) {
    const int col = c0 + cc;
    float ref = 0.f;
    for (int m = 0; m < 128; ++m)
      ref += bfval(f2bf(adj[(size_t)row * NN + m])) * bfval(f2bf(h[m * 64 + col]));
    maxd = fmaxf(maxd, fabsf(cm[row * 64 + col] - ref));
  }
  if (maxd > 1e-5f) atomicOr(&flag, 1);
  __syncthreads();
  if (flag) {
    for (int i = 0; i < 150; ++i) __builtin_amdgcn_s_sleep(127);
  }
}

extern "C" void kernel_launch(void* const* d_in, const int* in_sizes, int n_in,
                              void* d_out, int out_size, void* d_ws, size_t ws_size,
                              hipStream_t stream) {
  const float* x   = (const float*)d_in[0];
  const float* adj = (const float*)d_in[1];
  const float* W1  = (const float*)d_in[2];
  const float* b1  = (const float*)d_in[3];
  const float* W2  = (const float*)d_in[4];
  const float* b2  = (const float*)d_in[5];
  float* out = (float*)d_out;

  const size_t HBF_B = (size_t)3 * 8192 * 64 * 2;  // 3 MB
  const size_t H_B   = (size_t)3 * 8192 * 64 * 4;  // 6 MB
  const size_t T_B   = (size_t)8192 * 64 * 4;      // 2 MB
  if (ws_size < HBF_B + H_B + T_B) {
    fill_sentinel<<<2048, 256, 0, stream>>>(out);
    return;
  }
  unsigned short* hbf = (unsigned short*)d_ws;
  float* h = (float*)((char*)d_ws + HBF_B);
  float* t = (float*)((char*)d_ws + HBF_B + H_B);

  // layer 1
  prep2<<<3 * 1024, 256, 0, stream>>>(x, W1, b1, h, hbf);
  mfma_probe<<<1, 64, 0, stream>>>(adj, h);  // canary
  gemm_mfma<<<512, 512, 0, stream>>>(adj, hbf, t);
  // layer 2
  prep2<<<3 * 1024, 256, 0, stream>>>(t, W2, b2, h, hbf);
  gemm_mfma<<<512, 512, 0, stream>>>(adj, hbf, out);
}

// Round 7
// 442.184 us; speedup vs baseline: 4.7559x; 1.4734x over previous
//
#include <hip/hip_runtime.h>

// RelGCN round 7: MFMA gemm with depth-3 rotating register pipeline (T3/T4 in
// source form; no barriers in K-loop -> compiler emits counted vmcnt waits).
//   prep : hbf[r] = bf16(in @ W[r] + b[r])  fragment-swizzled  (verified path)
//   gemm : out = tanh( sum_{r,k} adj[r] (f32->bf16 in-reg) @ hbf[r] )  [f32]
//          512 blocks x 8 waves, 16 rows/block, waves split 768 (r,k)-chunks,
//          3-slot register pipeline: issue chunk it+2 while computing chunk it.

#define NN 8192

typedef __attribute__((ext_vector_type(4))) float float4v;
typedef __attribute__((ext_vector_type(8))) short short8v;

__device__ inline unsigned short f2bf(float f) {
  unsigned int u = __builtin_bit_cast(unsigned int, f);
  return (unsigned short)((u + 0x7FFFu + ((u >> 16) & 1u)) >> 16);  // RNE
}

// grid = 3*1024; hbf[((r*1024 + m/8)*64 + j)*8 + (m&7)] = bf16(h[r][m][j])
__global__ __launch_bounds__(256) void prep(
    const float* __restrict__ in, const float* __restrict__ W,
    const float* __restrict__ b, unsigned short* __restrict__ hbf) {
  __shared__ float Ws[64 * 64];
  __shared__ float xs[8 * 64];
  const int tid = threadIdx.x;
  const int r = blockIdx.x >> 10;
  const int kb = blockIdx.x & 1023;
#pragma unroll
  for (int i = 0; i < 16; ++i) Ws[tid + i * 256] = W[r * 4096 + tid + i * 256];
  xs[tid] = in[(size_t)kb * 512 + tid];
  xs[tid + 256] = in[(size_t)kb * 512 + 256 + tid];
  __syncthreads();
#pragma unroll
  for (int idx = tid; idx < 512; idx += 256) {
    const int ml = idx >> 6;
    const int j = idx & 63;
    float acc = b[r * 64 + j];
#pragma unroll
    for (int f = 0; f < 64; ++f) acc += xs[ml * 64 + f] * Ws[f * 64 + j];
    hbf[((size_t)((r * 1024 + kb) * 64 + j)) * 8 + ml] = f2bf(acc);
  }
}

__global__ __launch_bounds__(512) void gemm_mfma(
    const float* __restrict__ adj, const unsigned short* __restrict__ hbf,
    float* __restrict__ out) {
  __shared__ float red[8][16 * 64];
  const int tid = threadIdx.x;
  const int w = tid >> 6;
  const int l = tid & 63;
  const int lrow = l & 15;
  const int lk = l >> 4;
  const int mb = blockIdx.x;
  const float* parow = adj + (size_t)(mb * 16 + lrow) * NN + lk * 8;

  float4v acc0 = {0.f, 0.f, 0.f, 0.f}, acc1 = acc0, acc2 = acc0, acc3 = acc0;

  // 3 pipeline slots, all statically named (rule #20: no runtime indexing)
  float4v pA0, pA1, qA0, qA1, sA0, sA1;
  short8v pB0, pB1, pB2, pB3, qB0, qB1, qB2, qB3, sB0, sB1, sB2, sB3;

#define ISSUE(IT, A0, A1, B0, B1, B2, B3)                                      \
  do {                                                                         \
    const int c_ = (IT)*8 + w;                                                 \
    const int r_ = c_ >> 8;                                                    \
    const int mm_ = (c_ & 255) << 5;                                           \
    const float* pav_ = parow + ((size_t)r_ << 26) + mm_;                      \
    A0 = *(const float4v*)pav_;                                                \
    A1 = *(const float4v*)(pav_ + 4);                                          \
    const unsigned short* pb_ =                                                \
        hbf + (size_t)(r_ * 1024 + (mm_ >> 3) + lk) * 512 + lrow * 8;          \
    B0 = *(const short8v*)(pb_);                                               \
    B1 = *(const short8v*)(pb_ + 128);                                         \
    B2 = *(const short8v*)(pb_ + 256);                                         \
    B3 = *(const short8v*)(pb_ + 384);                                         \
  } while (0)

#define COMPUTE(A0, A1, B0, B1, B2, B3)                                        \
  do {                                                                         \
    short8v av_;                                                               \
    av_[0] = (short)f2bf(A0[0]); av_[1] = (short)f2bf(A0[1]);                  \
    av_[2] = (short)f2bf(A0[2]); av_[3] = (short)f2bf(A0[3]);                  \
    av_[4] = (short)f2bf(A1[0]); av_[5] = (short)f2bf(A1[1]);                  \
    av_[6] = (short)f2bf(A1[2]); av_[7] = (short)f2bf(A1[3]);                  \
    acc0 = __builtin_amdgcn_mfma_f32_16x16x32_bf16(av_, B0, acc0, 0, 0, 0);    \
    acc1 = __builtin_amdgcn_mfma_f32_16x16x32_bf16(av_, B1, acc1, 0, 0, 0);    \
    acc2 = __builtin_amdgcn_mfma_f32_16x16x32_bf16(av_, B2, acc2, 0, 0, 0);    \
    acc3 = __builtin_amdgcn_mfma_f32_16x16x32_bf16(av_, B3, acc3, 0, 0, 0);    \
  } while (0)

  ISSUE(0, pA0, pA1, pB0, pB1, pB2, pB3);
  ISSUE(1, qA0, qA1, qB0, qB1, qB2, qB3);
#pragma unroll 1
  for (int it = 0; it < 96; it += 3) {
    ISSUE(it + 2, sA0, sA1, sB0, sB1, sB2, sB3);
    COMPUTE(pA0, pA1, pB0, pB1, pB2, pB3);
    if (it + 3 < 96) ISSUE(it + 3, pA0, pA1, pB0, pB1, pB2, pB3);
    COMPUTE(qA0, qA1, qB0, qB1, qB2, qB3);
    if (it + 4 < 96) ISSUE(it + 4, qA0, qA1, qB0, qB1, qB2, qB3);
    COMPUTE(sA0, sA1, sB0, sB1, sB2, sB3);
  }
#undef ISSUE
#undef COMPUTE

  // C layout (probe-verified): col = g*16 + (l&15), row = (l>>4)*4 + q
#pragma unroll
  for (int q = 0; q < 4; ++q) {
    red[w][(lk * 4 + q) * 64 + 0 + lrow] = acc0[q];
    red[w][(lk * 4 + q) * 64 + 16 + lrow] = acc1[q];
    red[w][(lk * 4 + q) * 64 + 32 + lrow] = acc2[q];
    red[w][(lk * 4 + q) * 64 + 48 + lrow] = acc3[q];
  }
  __syncthreads();
#pragma unroll
  for (int idx = tid; idx < 1024; idx += 512) {
    const int row = idx >> 6, col = idx & 63;
    float s = 0.f;
#pragma unroll
    for (int wb = 0; wb < 8; ++wb) s += red[wb][row * 64 + col];
    out[(size_t)(mb * 16 + row) * 64 + col] = tanhf(s);
  }
}

__global__ __launch_bounds__(256) void fill_sentinel(float* __restrict__ dst) {
  dst[blockIdx.x * 256 + threadIdx.x] = 7.0f;
}

extern "C" void kernel_launch(void* const* d_in, const int* in_sizes, int n_in,
                              void* d_out, int out_size, void* d_ws, size_t ws_size,
                              hipStream_t stream) {
  const float* x   = (const float*)d_in[0];
  const float* adj = (const float*)d_in[1];
  const float* W1  = (const float*)d_in[2];
  const float* b1  = (const float*)d_in[3];
  const float* W2  = (const float*)d_in[4];
  const float* b2  = (const float*)d_in[5];
  float* out = (float*)d_out;

  const size_t HBF_B = (size_t)3 * 8192 * 64 * 2;  // 3 MB
  const size_t T_B   = (size_t)8192 * 64 * 4;      // 2 MB
  if (ws_size < HBF_B + T_B) {
    fill_sentinel<<<2048, 256, 0, stream>>>(out);
    return;
  }
  unsigned short* hbf = (unsigned short*)d_ws;
  float* t = (float*)((char*)d_ws + HBF_B);

  // layer 1
  prep<<<3 * 1024, 256, 0, stream>>>(x, W1, b1, hbf);
  gemm_mfma<<<512, 512, 0, stream>>>(adj, hbf, t);
  // layer 2
  prep<<<3 * 1024, 256, 0, stream>>>(t, W2, b2, hbf);
  gemm_mfma<<<512, 512, 0, stream>>>(adj, hbf, out);
}

// Round 8
// 397.620 us; speedup vs baseline: 5.2889x; 1.1121x over previous
//
#include <hip/hip_runtime.h>

// RelGCN round 8: MFMA gemm with LDS-staged A (full-cacheline 256B-run staging),
// B direct from L2-resident hbf, 1 barrier/tile double buffer.
//   prep : hbf[r] = bf16(in @ W[r] + b[r])  fragment-swizzled  (verified)
//   gemm : out = tanh( sum_{r,k} adj[r] @ hbf[r] )   [f32 out]
//          512 blocks x 4 waves, 16 rows/block; 96 tiles of 256-k; per tile:
//          B-loads first (vmcnt retire order), reg-stage tile t+1, compute 2
//          chunks/wave from LDS, ds_write, barrier.

#define NN 8192
#define TS 260  // padded LDS row stride in floats (1040B: uniform bank spread)

typedef __attribute__((ext_vector_type(4))) float float4v;
typedef __attribute__((ext_vector_type(8))) short short8v;

__device__ inline unsigned short f2bf(float f) {
  unsigned int u = __builtin_bit_cast(unsigned int, f);
  return (unsigned short)((u + 0x7FFFu + ((u >> 16) & 1u)) >> 16);  // RNE
}

// grid = 3*1024; hbf[((r*1024 + m/8)*64 + j)*8 + (m&7)] = bf16(h[r][m][j])
__global__ __launch_bounds__(256) void prep(
    const float* __restrict__ in, const float* __restrict__ W,
    const float* __restrict__ b, unsigned short* __restrict__ hbf) {
  __shared__ float Ws[64 * 64];
  __shared__ float xs[8 * 64];
  const int tid = threadIdx.x;
  const int r = blockIdx.x >> 10;
  const int kb = blockIdx.x & 1023;
#pragma unroll
  for (int i = 0; i < 16; ++i) Ws[tid + i * 256] = W[r * 4096 + tid + i * 256];
  xs[tid] = in[(size_t)kb * 512 + tid];
  xs[tid + 256] = in[(size_t)kb * 512 + 256 + tid];
  __syncthreads();
#pragma unroll
  for (int idx = tid; idx < 512; idx += 256) {
    const int ml = idx >> 6;
    const int j = idx & 63;
    float acc = b[r * 64 + j];
#pragma unroll
    for (int f = 0; f < 64; ++f) acc += xs[ml * 64 + f] * Ws[f * 64 + j];
    hbf[((size_t)((r * 1024 + kb) * 64 + j)) * 8 + ml] = f2bf(acc);
  }
}

__global__ __launch_bounds__(256) void gemm_mfma(
    const float* __restrict__ adj, const unsigned short* __restrict__ hbf,
    float* __restrict__ out) {
  __shared__ float lds[2 * 16 * TS];  // two 16x256 A tiles (padded), 33.3 KB
  const int tid = threadIdx.x;
  const int w = tid >> 6;       // wave 0..3
  const int l = tid & 63;
  const int lrow = l & 15;
  const int lk = l >> 4;
  const int mb = blockIdx.x;

  // staging map: thread -> (row, 16B segment); each instr = 16 rows x 256B runs
  const int srow = tid >> 4;    // 0..15
  const int sseg = tid & 15;    // 0..15
  const float* adjrow = adj + (size_t)(mb * 16 + srow) * NN + sseg * 4;
  float* buf0 = lds;
  float* buf1 = lds + 16 * TS;

  float4v acc0 = {0.f, 0.f, 0.f, 0.f}, acc1 = acc0, acc2 = acc0, acc3 = acc0;
  float4v sA0, sA1, sA2, sA3;

#define GLOAD(T)                                                               \
  do {                                                                         \
    const int r_ = (T) >> 5;                                                   \
    const size_t off_ = ((size_t)r_ << 26) + (((T) & 31) << 8);                \
    sA0 = *(const float4v*)(adjrow + off_);                                    \
    sA1 = *(const float4v*)(adjrow + off_ + 64);                               \
    sA2 = *(const float4v*)(adjrow + off_ + 128);                              \
    sA3 = *(const float4v*)(adjrow + off_ + 192);                              \
  } while (0)

#define DSWRITE(B)                                                             \
  do {                                                                         \
    float* p_ = (B) + srow * TS + sseg * 4;                                    \
    *(float4v*)(p_) = sA0;                                                     \
    *(float4v*)(p_ + 64) = sA1;                                                \
    *(float4v*)(p_ + 128) = sA2;                                               \
    *(float4v*)(p_ + 192) = sA3;                                               \
  } while (0)

  GLOAD(0);
  DSWRITE(buf0);
  __syncthreads();

  short8v b00, b01, b02, b03, b10, b11, b12, b13;

#pragma unroll 1
  for (int t = 0; t < 96; ++t) {
    const float* cur = (t & 1) ? buf1 : buf0;
    const int r_ = t >> 5;
    const int kb_ = (t & 31) << 8;
    // B-loads FIRST (oldest in vmcnt queue -> retire at L2 latency)
    {
      const int mm0 = kb_ + (w * 2) * 32;
      const unsigned short* pb0 =
          hbf + (size_t)(r_ * 1024 + (mm0 >> 3) + lk) * 512 + lrow * 8;
      b00 = *(const short8v*)(pb0);
      b01 = *(const short8v*)(pb0 + 128);
      b02 = *(const short8v*)(pb0 + 256);
      b03 = *(const short8v*)(pb0 + 384);
      const unsigned short* pb1 = pb0 + 4 * 512;  // mm0+32 -> +4 groups
      b10 = *(const short8v*)(pb1);
      b11 = *(const short8v*)(pb1 + 128);
      b12 = *(const short8v*)(pb1 + 256);
      b13 = *(const short8v*)(pb1 + 384);
    }
    if (t < 95) GLOAD(t + 1);
    // chunk 0: cc = w*2
    {
      const float* ap = cur + lrow * TS + (w * 2) * 32 + lk * 8;
      const float4v a0 = *(const float4v*)ap;
      const float4v a1 = *(const float4v*)(ap + 4);
      short8v av;
      av[0] = (short)f2bf(a0[0]); av[1] = (short)f2bf(a0[1]);
      av[2] = (short)f2bf(a0[2]); av[3] = (short)f2bf(a0[3]);
      av[4] = (short)f2bf(a1[0]); av[5] = (short)f2bf(a1[1]);
      av[6] = (short)f2bf(a1[2]); av[7] = (short)f2bf(a1[3]);
      acc0 = __builtin_amdgcn_mfma_f32_16x16x32_bf16(av, b00, acc0, 0, 0, 0);
      acc1 = __builtin_amdgcn_mfma_f32_16x16x32_bf16(av, b01, acc1, 0, 0, 0);
      acc2 = __builtin_amdgcn_mfma_f32_16x16x32_bf16(av, b02, acc2, 0, 0, 0);
      acc3 = __builtin_amdgcn_mfma_f32_16x16x32_bf16(av, b03, acc3, 0, 0, 0);
    }
    // chunk 1: cc = w*2+1
    {
      const float* ap = cur + lrow * TS + (w * 2 + 1) * 32 + lk * 8;
      const float4v a0 = *(const float4v*)ap;
      const float4v a1 = *(const float4v*)(ap + 4);
      short8v av;
      av[0] = (short)f2bf(a0[0]); av[1] = (short)f2bf(a0[1]);
      av[2] = (short)f2bf(a0[2]); av[3] = (short)f2bf(a0[3]);
      av[4] = (short)f2bf(a1[0]); av[5] = (short)f2bf(a1[1]);
      av[6] = (short)f2bf(a1[2]); av[7] = (short)f2bf(a1[3]);
      acc0 = __builtin_amdgcn_mfma_f32_16x16x32_bf16(av, b10, acc0, 0, 0, 0);
      acc1 = __builtin_amdgcn_mfma_f32_16x16x32_bf16(av, b11, acc1, 0, 0, 0);
      acc2 = __builtin_amdgcn_mfma_f32_16x16x32_bf16(av, b12, acc2, 0, 0, 0);
      acc3 = __builtin_amdgcn_mfma_f32_16x16x32_bf16(av, b13, acc3, 0, 0, 0);
    }
    if (t < 95) DSWRITE((t & 1) ? buf0 : buf1);
    __syncthreads();
  }
#undef GLOAD
#undef DSWRITE

  // epilogue: red[4][1024] aliased onto lds (compute done; per-wave partials)
  float* red = lds;
#pragma unroll
  for (int q = 0; q < 4; ++q) {
    red[w * 1024 + (lk * 4 + q) * 64 + 0 + lrow] = acc0[q];
    red[w * 1024 + (lk * 4 + q) * 64 + 16 + lrow] = acc1[q];
    red[w * 1024 + (lk * 4 + q) * 64 + 32 + lrow] = acc2[q];
    red[w * 1024 + (lk * 4 + q) * 64 + 48 + lrow] = acc3[q];
  }
  __syncthreads();
#pragma unroll
  for (int idx = tid; idx < 1024; idx += 256) {
    const float s = red[idx] + red[1024 + idx] + red[2048 + idx] + red[3072 + idx];
    out[(size_t)mb * 1024 + idx] = tanhf(s);
  }
}

__global__ __launch_bounds__(256) void fill_sentinel(float* __restrict__ dst) {
  dst[blockIdx.x * 256 + threadIdx.x] = 7.0f;
}

extern "C" void kernel_launch(void* const* d_in, const int* in_sizes, int n_in,
                              void* d_out, int out_size, void* d_ws, size_t ws_size,
                              hipStream_t stream) {
  const float* x   = (const float*)d_in[0];
  const float* adj = (const float*)d_in[1];
  const float* W1  = (const float*)d_in[2];
  const float* b1  = (const float*)d_in[3];
  const float* W2  = (const float*)d_in[4];
  const float* b2  = (const float*)d_in[5];
  float* out = (float*)d_out;

  const size_t HBF_B = (size_t)3 * 8192 * 64 * 2;  // 3 MB
  const size_t T_B   = (size_t)8192 * 64 * 4;      // 2 MB
  if (ws_size < HBF_B + T_B) {
    fill_sentinel<<<2048, 256, 0, stream>>>(out);
    return;
  }
  unsigned short* hbf = (unsigned short*)d_ws;
  float* t = (float*)((char*)d_ws + HBF_B);

  // layer 1
  prep<<<3 * 1024, 256, 0, stream>>>(x, W1, b1, hbf);
  gemm_mfma<<<512, 256, 0, stream>>>(adj, hbf, t);
  // layer 2
  prep<<<3 * 1024, 256, 0, stream>>>(t, W2, b2, hbf);
  gemm_mfma<<<512, 256, 0, stream>>>(adj, hbf, out);
}